// Round 1
// 1925.761 us; speedup vs baseline: 1.3909x; 1.3909x over previous
//
#include <hip/hip_runtime.h>

typedef unsigned short u16;
typedef unsigned long long u64;
typedef __bf16 bf16x8 __attribute__((ext_vector_type(8)));
typedef float f32x4 __attribute__((ext_vector_type(4)));

#define AS1 __attribute__((address_space(1)))
#define AS3 __attribute__((address_space(3)))

__device__ __forceinline__ u16 f2bf(float f) {
  unsigned u = __builtin_bit_cast(unsigned, f);
  unsigned r = (u + 0x7FFFu + ((u >> 16) & 1u)) >> 16;
  return (u16)r;
}
__device__ __forceinline__ float bf2f(u16 h) {
  unsigned u = ((unsigned)h) << 16;
  return __builtin_bit_cast(float, u);
}

// Coherent (MALL-level, sc0 sc1) 8B data movement for cross-WG h hand-off.
// No fences anywhere: ordering is waitcnt-drain before the barrier flag.
__device__ __forceinline__ u64 ld_coh_u64(const u64* p) {
  return __hip_atomic_load(p, __ATOMIC_RELAXED, __HIP_MEMORY_SCOPE_SYSTEM);
}
__device__ __forceinline__ void st_coh_u64(u64* p, u64 v) {
  __hip_atomic_store(p, v, __ATOMIC_RELAXED, __HIP_MEMORY_SCOPE_SYSTEM);
}

// ---- problem constants ----
constexpr int V = 32000, E = 256, H = 512, T = 64, B = 64;
constexpr int H3 = 3 * H;            // 1536
constexpr int MP = T * B;            // 4096 (padded M)
constexpr int MD = (T - 1) * B;      // 4032 (valid decoder rows)
constexpr int KO = H + E;            // 768
constexpr long long OUT_LOGITS_OFF = (long long)B * V;    // 2,048,000
constexpr long long OUT_LOSS_OFF  = (long long)T * B * V; // 131,072,000

// ======================================================================
// Weight cast fp32 -> bf16 (enc_Wih, dec_Wih, Wout)
// ======================================================================
__global__ __launch_bounds__(256) void cast_weights(
    const float* __restrict__ eW, const float* __restrict__ dW,
    const float* __restrict__ oW,
    u16* __restrict__ eWb, u16* __restrict__ dWb, u16* __restrict__ oWb)
{
  size_t i = (size_t)blockIdx.x * 256 + threadIdx.x;
  const size_t S1 = (size_t)H3 * E;       // 393216
  if (i < S1) { eWb[i] = f2bf(eW[i]); return; }
  i -= S1;
  if (i < S1) { dWb[i] = f2bf(dW[i]); return; }
  i -= S1;
  if (i < (size_t)V * KO) oWb[i] = f2bf(oW[i]);
}

// ======================================================================
// Embedding gather: Aenc[4096][256] (bf16), Afinal[.][512..768) = emb[y[:-1]]
// ======================================================================
__global__ __launch_bounds__(256) void gather_emb(
    const int* __restrict__ x, const int* __restrict__ y,
    const float* __restrict__ emb,
    u16* __restrict__ Aenc, u16* __restrict__ Afin)
{
  const int blk = blockIdx.x, e = threadIdx.x;
  if (blk < MP) {
    int tok = x[blk];
    Aenc[(size_t)blk * E + e] = f2bf(emb[(size_t)tok * E + e]);
  } else {
    int m = blk - MP;
    int tok = (m < MD) ? y[m] : 0;
    Afin[(size_t)m * KO + H + e] = f2bf(emb[(size_t)tok * E + e]);
  }
}

// ======================================================================
// NT GEMM: C[M,N] = A[M,K] * W[N,K]^T + bias, bf16 inputs, fp32 acc.
// 128x128 tile, BK=32, m97 structure (global_load_lds width 16, XOR-swizzled
// LDS chunks for 2-way-max bank aliasing on ds_read_b128).
// ======================================================================
__global__ __launch_bounds__(256) void gemm_nt(
    const u16* __restrict__ A, int lda,
    const u16* __restrict__ W, int ldw,
    const float* __restrict__ bias,
    int Kt,                                   // K / 32
    float* __restrict__ Cf, u16* __restrict__ Cb,  // exactly one non-null
    int ldc, int Mvalid)
{
  __shared__ u16 a_sm[128 * 32];
  __shared__ u16 b_sm[128 * 32];
  const int tid = threadIdx.x;
  const int lane = tid & 63;
  const int w = tid >> 6;
  const int m0 = blockIdx.x * 128;
  const int n0 = blockIdx.y * 128;
  const int srow = lane >> 2;                        // staging row within 16
  const int gc = (lane & 3) ^ ((lane >> 3) & 3);     // swizzled global chunk
  const int r = lane & 15;
  const int q = lane >> 4;
  const int cx = (r >> 1) & 3;                       // frag chunk xor
  const int wr = w >> 1, wc = w & 1;

  f32x4 acc[4][4] = {};

  for (int kt = 0; kt < Kt; ++kt) {
    const int k0 = kt * 32;
    __syncthreads();
#pragma unroll
    for (int rr = 0; rr < 2; ++rr) {
      const int rbase = w * 32 + rr * 16;
      const u16* gA = A + (size_t)(m0 + rbase + srow) * lda + k0 + gc * 8;
      const u16* gB = W + (size_t)(n0 + rbase + srow) * ldw + k0 + gc * 8;
      __builtin_amdgcn_global_load_lds((const AS1 void*)gA,
                                       (AS3 void*)&a_sm[rbase * 32], 16, 0, 0);
      __builtin_amdgcn_global_load_lds((const AS1 void*)gB,
                                       (AS3 void*)&b_sm[rbase * 32], 16, 0, 0);
    }
    __syncthreads();
    bf16x8 af[4], bfv[4];
#pragma unroll
    for (int i = 0; i < 4; ++i) {
      af[i]  = *(const bf16x8*)&a_sm[(wr * 64 + i * 16 + r) * 32 + ((q ^ cx) * 8)];
      bfv[i] = *(const bf16x8*)&b_sm[(wc * 64 + i * 16 + r) * 32 + ((q ^ cx) * 8)];
    }
#pragma unroll
    for (int i = 0; i < 4; ++i)
#pragma unroll
      for (int j = 0; j < 4; ++j)
        acc[i][j] = __builtin_amdgcn_mfma_f32_16x16x32_bf16(af[i], bfv[j], acc[i][j], 0, 0, 0);
  }

#pragma unroll
  for (int i = 0; i < 4; ++i) {
#pragma unroll
    for (int j = 0; j < 4; ++j) {
      const int n = n0 + wc * 64 + j * 16 + r;
      const float bv = bias ? bias[n] : 0.f;
#pragma unroll
      for (int v = 0; v < 4; ++v) {
        const int m = m0 + wr * 64 + i * 16 + q * 4 + v;
        if (m < Mvalid) {
          const float val = acc[i][j][v] + bv;
          if (Cf) Cf[(size_t)m * ldc + n] = val;
          else    Cb[(size_t)m * ldc + n] = f2bf(val);
        }
      }
    }
  }
}

// ======================================================================
// Persistent GRU. 32 WGs, WG w owns H-slice [w*16, w*16+16).
// h carried in fp32 (WG-private, plain cached) + bf16 (cross-WG broadcast).
// Cross-WG coherence: all bf16-h traffic uses relaxed SYSTEM-scope atomic
// 8B ops (sc0 sc1 -> coherent at MALL, bypasses L1/L2). Barrier = relaxed
// atomic counter; release ordering = explicit s_waitcnt vmcnt(0) before the
// flag add. NO acquire/release fences -> no per-step L2 writeback/invalidate,
// so xgates/Whh/bhh/lens/hf stay cached.
// ======================================================================
__global__ __launch_bounds__(256) void gru_kernel(
    const u16* __restrict__ xgates,     // [steps*64, 1536] bf16 (incl. b_ih)
    const float* __restrict__ Whh,      // [1536, 512] fp32
    const float* __restrict__ bhh,      // [1536]
    const int* __restrict__ lens,       // null => no masking
    const float* __restrict__ h0,       // null => zeros
    float* __restrict__ hf0, float* __restrict__ hf1,
    u16* __restrict__ hb0, u16* __restrict__ hb1,
    int steps, unsigned* __restrict__ bar,
    u16* __restrict__ outA)             // null, or Afinal: [m*768 + j] bf16
{
  extern __shared__ char smem[];
  u16* whh_sm = (u16*)smem;                        // [48][520] bf16
  u16* h_sm   = (u16*)(smem + 48 * 520 * 2);       // [64][520] bf16
  float* hg_sm = (float*)(smem + 112 * 520 * 2);   // [64][3][16] fp32

  const int tid = threadIdx.x;
  const int lane = tid & 63;
  const int w = tid >> 6;
  const int jbase = blockIdx.x * 16;
  const int r = lane & 15, q = lane >> 4;

  // preload this WG's 48 Whh rows (r,z,n gates for its 16 H-indices)
  for (int e = tid; e < 48 * 512; e += 256) {
    int rowl = e >> 9, k = e & 511;
    int g = rowl >> 4, jl = rowl & 15;
    whh_sm[rowl * 520 + k] = f2bf(Whh[(size_t)(g * 512 + jbase + jl) * 512 + k]);
  }

  // elementwise ownership: thread -> (b = tid>>2, 4 consecutive jl)
  const int eb  = tid >> 2;
  const int jl0 = (tid & 3) * 4;
  const int jg0 = jbase + jl0;

  // init h slice (bf16 part via coherent stores)
  {
    u16 hb4[4];
#pragma unroll
    for (int v2 = 0; v2 < 4; ++v2) {
      float v = h0 ? h0[eb * 512 + jg0 + v2] : 0.f;
      hf0[eb * 512 + jg0 + v2] = v;
      hb4[v2] = f2bf(v);
    }
    u64 pack = (u64)hb4[0] | ((u64)hb4[1] << 16) | ((u64)hb4[2] << 32) |
               ((u64)hb4[3] << 48);
    st_coh_u64((u64*)&hb0[eb * 512 + jg0], pack);
  }
  asm volatile("s_waitcnt vmcnt(0)" ::: "memory");
  __syncthreads();
  if (tid == 0) {
    __hip_atomic_fetch_add(bar, 1u, __ATOMIC_RELAXED, __HIP_MEMORY_SCOPE_SYSTEM);
    while (__hip_atomic_load(bar, __ATOMIC_RELAXED, __HIP_MEMORY_SCOPE_SYSTEM) < 32u)
      __builtin_amdgcn_s_sleep(1);
  }
  __syncthreads();

  for (int t = 0; t < steps; ++t) {
    const float* hf_cur = (t & 1) ? hf1 : hf0;
    const u16*   hb_cur = (t & 1) ? hb1 : hb0;
    float*       hf_nxt = (t & 1) ? hf0 : hf1;
    u16*         hb_nxt = (t & 1) ? hb0 : hb1;

    // prefetch this step's input gates early (plain cached loads; no h dep)
    const size_t mrow = (size_t)t * 64 + eb;
    u64 xrv = *(const u64*)&xgates[mrow * 1536 + jg0];
    u64 xzv = *(const u64*)&xgates[mrow * 1536 + 512 + jg0];
    u64 xnv = *(const u64*)&xgates[mrow * 1536 + 1024 + jg0];

    // stage full h (bf16) into LDS: 32 coherent 8B loads in flight/thread
    {
      const u64* src = (const u64*)hb_cur;   // 8192 chunks = 64 rows x 128
      u64 v[32];
#pragma unroll
      for (int i = 0; i < 32; ++i) v[i] = ld_coh_u64(src + i * 256 + tid);
#pragma unroll
      for (int i = 0; i < 32; ++i) {
        int c = i * 256 + tid;
        int row = c >> 7, c4 = c & 127;
        *(u64*)&h_sm[row * 520 + c4 * 4] = v[i];
      }
    }
    __syncthreads();

    // hg[b, 48 rows] = h @ Whh_slice^T ; wave w -> b-block w*16
    f32x4 acc[3] = {};
#pragma unroll
    for (int kt = 0; kt < 16; ++kt) {
      bf16x8 a = *(const bf16x8*)&h_sm[(w * 16 + r) * 520 + kt * 32 + q * 8];
#pragma unroll
      for (int g = 0; g < 3; ++g) {
        bf16x8 bb = *(const bf16x8*)&whh_sm[(g * 16 + r) * 520 + kt * 32 + q * 8];
        acc[g] = __builtin_amdgcn_mfma_f32_16x16x32_bf16(a, bb, acc[g], 0, 0, 0);
      }
    }
#pragma unroll
    for (int g = 0; g < 3; ++g)
#pragma unroll
      for (int v = 0; v < 4; ++v)
        hg_sm[((w * 16 + q * 4 + v) * 3 + g) * 16 + r] = acc[g][v];
    __syncthreads();

    // elementwise gates (fp32 carry path), 4 consecutive j per thread
    {
      u16 hb4[4];
#pragma unroll
      for (int v2 = 0; v2 < 4; ++v2) {
        const int jl = jl0 + v2, jg = jg0 + v2;
        float xr = bf2f((u16)(xrv >> (16 * v2)));
        float xz = bf2f((u16)(xzv >> (16 * v2)));
        float xn = bf2f((u16)(xnv >> (16 * v2)));
        float hr = hg_sm[(eb * 3 + 0) * 16 + jl] + bhh[jg];
        float hz = hg_sm[(eb * 3 + 1) * 16 + jl] + bhh[512 + jg];
        float hn = hg_sm[(eb * 3 + 2) * 16 + jl] + bhh[1024 + jg];
        float rg = 1.f / (1.f + __expf(-(xr + hr)));
        float zg = 1.f / (1.f + __expf(-(xz + hz)));
        float ng = tanhf(xn + rg * hn);
        float hold = hf_cur[eb * 512 + jg];
        float hnew = (1.f - zg) * ng + zg * hold;
        if (lens && t >= lens[eb]) hnew = hold;
        hf_nxt[eb * 512 + jg] = hnew;
        hb4[v2] = f2bf(hnew);
        if (outA) outA[mrow * (size_t)KO + jg] = hb4[v2];
      }
      u64 pack = (u64)hb4[0] | ((u64)hb4[1] << 16) | ((u64)hb4[2] << 32) |
                 ((u64)hb4[3] << 48);
      st_coh_u64((u64*)&hb_nxt[eb * 512 + jg0], pack);
    }

    // release: drain coherent stores, then count in; spin until all 32 in
    asm volatile("s_waitcnt vmcnt(0)" ::: "memory");
    __syncthreads();
    if (tid == 0) {
      __hip_atomic_fetch_add(bar, 1u, __ATOMIC_RELAXED, __HIP_MEMORY_SCOPE_SYSTEM);
      const unsigned tgt = 32u * (unsigned)(t + 2);
      while (__hip_atomic_load(bar, __ATOMIC_RELAXED, __HIP_MEMORY_SCOPE_SYSTEM) < tgt)
        __builtin_amdgcn_s_sleep(1);
    }
    __syncthreads();
  }
}

// ======================================================================
// Loss: one WG per row; online logsumexp; masked NLL accumulate.
// ======================================================================
__global__ __launch_bounds__(256) void loss_rows(
    const float* __restrict__ logits, const int* __restrict__ y,
    float* __restrict__ accum)
{
  __shared__ float sm_m[256], sm_s[256];
  const int row = blockIdx.x;
  const float* rp = logits + (size_t)row * V;
  const int tid = threadIdx.x;
  float m = -1e30f, s = 0.f;
  for (int it = 0; it < 32; ++it) {
    int i4 = tid + it * 256;
    if (i4 < V / 4) {
      float4 x = ((const float4*)rp)[i4];
      float mx = fmaxf(fmaxf(x.x, x.y), fmaxf(x.z, x.w));
      float mn = fmaxf(m, mx);
      s = s * __expf(m - mn) + __expf(x.x - mn) + __expf(x.y - mn) +
          __expf(x.z - mn) + __expf(x.w - mn);
      m = mn;
    }
  }
  sm_m[tid] = m; sm_s[tid] = s;
  __syncthreads();
  for (int off = 128; off > 0; off >>= 1) {
    if (tid < off) {
      float m2 = sm_m[tid + off], s2 = sm_s[tid + off];
      float mn = fmaxf(sm_m[tid], m2);
      sm_s[tid] = sm_s[tid] * __expf(sm_m[tid] - mn) + s2 * __expf(m2 - mn);
      sm_m[tid] = mn;
    }
    __syncthreads();
  }
  if (tid == 0) {
    int tgt = y[row + 64];                 // y[1:] flattened
    float lse = sm_m[0] + __logf(sm_s[0]);
    float nll = lse - rp[tgt];
    if (tgt != 0) {                        // PAD = 0
      atomicAdd(&accum[0], nll);
      atomicAdd(&accum[1], 1.f);
    }
  }
}

__global__ void finalize_loss(const float* __restrict__ accum, float* __restrict__ out) {
  out[0] = accum[0] / fmaxf(accum[1], 1.f);
}

// ======================================================================
extern "C" void kernel_launch(void* const* d_in, const int* in_sizes, int n_in,
                              void* d_out, int out_size, void* d_ws, size_t ws_size,
                              hipStream_t stream)
{
  const int*   x      = (const int*)d_in[0];
  const int*   x_lens = (const int*)d_in[1];
  const int*   y      = (const int*)d_in[2];
  const float* emb    = (const float*)d_in[3];
  const float* eWih   = (const float*)d_in[4];
  const float* eWhh   = (const float*)d_in[5];
  const float* ebih   = (const float*)d_in[6];
  const float* ebhh   = (const float*)d_in[7];
  const float* dWih   = (const float*)d_in[8];
  const float* dWhh   = (const float*)d_in[9];
  const float* dbih   = (const float*)d_in[10];
  const float* dbhh   = (const float*)d_in[11];
  const float* Wout   = (const float*)d_in[12];
  const float* bout   = (const float*)d_in[13];
  float* out = (float*)d_out;

  char* ws = (char*)d_ws;
  unsigned* cnt  = (unsigned*)(ws + 0);            // [0]=bar_enc [1]=bar_dec
  float*    accum = (float*)(ws + 8);              // [0]=nll sum [1]=count
  u16*   Aenc = (u16*)(ws + 256);                  // 4096x256 bf16
  u16*   Afin = (u16*)(ws + 2097408);              // 4096x768 bf16
  u16*   xg   = (u16*)(ws + 8388864);              // 4096x1536 bf16
  u16*   yg   = (u16*)(ws + 20971776);             // 4096x1536 bf16
  u16*   WEb  = (u16*)(ws + 33554688);             // 1536x256
  u16*   WDb  = (u16*)(ws + 34341120);             // 1536x256
  u16*   WOb  = (u16*)(ws + 35127552);             // 32000x768
  float* hEf  = (float*)(ws + 84279552);           // 2 x [64x512] fp32
  u16*   hEb  = (u16*)(ws + 84541696);             // 2 x [64x512] bf16
  float* hDf  = (float*)(ws + 84672768);
  u16*   hDb  = (u16*)(ws + 84934912);

  // dec_out[0] = zeros; barrier/accum init
  hipMemsetAsync(d_out, 0, (size_t)B * V * sizeof(float), stream);
  hipMemsetAsync(ws, 0, 256, stream);

  cast_weights<<<99072, 256, 0, stream>>>(eWih, dWih, Wout, WEb, WDb, WOb);
  gather_emb<<<2 * MP, 256, 0, stream>>>(x, y, emb, Aenc, Afin);

  // input gates
  gemm_nt<<<dim3(32, 12), 256, 0, stream>>>(Aenc, E, WEb, E, ebih, E / 32,
                                            nullptr, xg, H3, MP);
  gemm_nt<<<dim3(32, 12), 256, 0, stream>>>(Afin + H, KO, WDb, E, dbih, E / 32,
                                            nullptr, yg, H3, MP);

  const size_t gru_lds = (size_t)112 * 520 * 2 + (size_t)64 * 3 * 16 * 4; // 128,768 B
  // encoder: 64 steps, masked by x_lens, h0 = 0; final h lands in buffer 0
  gru_kernel<<<32, 256, gru_lds, stream>>>(xg, eWhh, ebhh, x_lens, nullptr,
      hEf, hEf + 32768, hEb, hEb + 32768, T, cnt + 0, nullptr);
  // decoder: 63 steps, h0 = encoder final (hEf buf0), dumps dec_h into Afinal
  gru_kernel<<<32, 256, gru_lds, stream>>>(yg, dWhh, dbhh, nullptr, hEf,
      hDf, hDf + 32768, hDb, hDb + 32768, T - 1, cnt + 1, Afin);

  // logits = [dec_h, ey] @ Wout^T + bout  -> d_out rows 1..63
  gemm_nt<<<dim3(32, 250), 256, 0, stream>>>(Afin, KO, WOb, KO, bout, KO / 32,
      out + OUT_LOGITS_OFF, nullptr, V, MD);

  loss_rows<<<MD, 256, 0, stream>>>(out + OUT_LOGITS_OFF, y, accum);
  finalize_loss<<<1, 1, 0, stream>>>(accum, out + OUT_LOSS_OFF);
}

// Round 2
// 1842.760 us; speedup vs baseline: 1.4535x; 1.0450x over previous
//
#include <hip/hip_runtime.h>

typedef unsigned short u16;
typedef unsigned long long u64;
typedef __bf16 bf16x8 __attribute__((ext_vector_type(8)));
typedef float f32x4 __attribute__((ext_vector_type(4)));

#define AS1 __attribute__((address_space(1)))
#define AS3 __attribute__((address_space(3)))

__device__ __forceinline__ u16 f2bf(float f) {
  unsigned u = __builtin_bit_cast(unsigned, f);
  unsigned r = (u + 0x7FFFu + ((u >> 16) & 1u)) >> 16;
  return (u16)r;
}
__device__ __forceinline__ float bf2f(u16 h) {
  unsigned u = ((unsigned)h) << 16;
  return __builtin_bit_cast(float, u);
}

// Coherent (MALL-level, sc0 sc1) 8B data movement for cross-WG h hand-off.
__device__ __forceinline__ u64 ld_coh_u64(const u64* p) {
  return __hip_atomic_load(p, __ATOMIC_RELAXED, __HIP_MEMORY_SCOPE_SYSTEM);
}
__device__ __forceinline__ void st_coh_u64(u64* p, u64 v) {
  __hip_atomic_store(p, v, __ATOMIC_RELAXED, __HIP_MEMORY_SCOPE_SYSTEM);
}

// ---- problem constants ----
constexpr int V = 32000, E = 256, H = 512, T = 64, B = 64;
constexpr int H3 = 3 * H;            // 1536
constexpr int MP = T * B;            // 4096 (padded M)
constexpr int MD = (T - 1) * B;      // 4032 (valid decoder rows)
constexpr int KO = H + E;            // 768
constexpr long long OUT_LOGITS_OFF = (long long)B * V;    // 2,048,000
constexpr long long OUT_LOSS_OFF  = (long long)T * B * V; // 131,072,000

// ======================================================================
// Weight cast fp32 -> bf16 (enc_Wih, dec_Wih, Wout)
// ======================================================================
__global__ __launch_bounds__(256) void cast_weights(
    const float* __restrict__ eW, const float* __restrict__ dW,
    const float* __restrict__ oW,
    u16* __restrict__ eWb, u16* __restrict__ dWb, u16* __restrict__ oWb)
{
  size_t i = (size_t)blockIdx.x * 256 + threadIdx.x;
  const size_t S1 = (size_t)H3 * E;       // 393216
  if (i < S1) { eWb[i] = f2bf(eW[i]); return; }
  i -= S1;
  if (i < S1) { dWb[i] = f2bf(dW[i]); return; }
  i -= S1;
  if (i < (size_t)V * KO) oWb[i] = f2bf(oW[i]);
}

// ======================================================================
// Embedding gather: Aenc[4096][256] (bf16), Afinal[.][512..768) = emb[y[:-1]]
// ======================================================================
__global__ __launch_bounds__(256) void gather_emb(
    const int* __restrict__ x, const int* __restrict__ y,
    const float* __restrict__ emb,
    u16* __restrict__ Aenc, u16* __restrict__ Afin)
{
  const int blk = blockIdx.x, e = threadIdx.x;
  if (blk < MP) {
    int tok = x[blk];
    Aenc[(size_t)blk * E + e] = f2bf(emb[(size_t)tok * E + e]);
  } else {
    int m = blk - MP;
    int tok = (m < MD) ? y[m] : 0;
    Afin[(size_t)m * KO + H + e] = f2bf(emb[(size_t)tok * E + e]);
  }
}

// ======================================================================
// NT GEMM (small): 128x128 tile, BK=32, m97 structure. Used for the two
// gate GEMMs (N=1536, K=256) where grid size needs the smaller tile.
// ======================================================================
__global__ __launch_bounds__(256) void gemm_nt(
    const u16* __restrict__ A, int lda,
    const u16* __restrict__ W, int ldw,
    const float* __restrict__ bias,
    int Kt,                                   // K / 32
    float* __restrict__ Cf, u16* __restrict__ Cb,  // exactly one non-null
    int ldc, int Mvalid)
{
  __shared__ u16 a_sm[128 * 32];
  __shared__ u16 b_sm[128 * 32];
  const int tid = threadIdx.x;
  const int lane = tid & 63;
  const int w = tid >> 6;
  const int m0 = blockIdx.x * 128;
  const int n0 = blockIdx.y * 128;
  const int srow = lane >> 2;                        // staging row within 16
  const int gc = (lane & 3) ^ ((lane >> 3) & 3);     // swizzled global chunk
  const int r = lane & 15;
  const int q = lane >> 4;
  const int cx = (r >> 1) & 3;                       // frag chunk xor
  const int wr = w >> 1, wc = w & 1;

  f32x4 acc[4][4] = {};

  for (int kt = 0; kt < Kt; ++kt) {
    const int k0 = kt * 32;
    __syncthreads();
#pragma unroll
    for (int rr = 0; rr < 2; ++rr) {
      const int rbase = w * 32 + rr * 16;
      const u16* gA = A + (size_t)(m0 + rbase + srow) * lda + k0 + gc * 8;
      const u16* gB = W + (size_t)(n0 + rbase + srow) * ldw + k0 + gc * 8;
      __builtin_amdgcn_global_load_lds((const AS1 void*)gA,
                                       (AS3 void*)&a_sm[rbase * 32], 16, 0, 0);
      __builtin_amdgcn_global_load_lds((const AS1 void*)gB,
                                       (AS3 void*)&b_sm[rbase * 32], 16, 0, 0);
    }
    __syncthreads();
    bf16x8 af[4], bfv[4];
#pragma unroll
    for (int i = 0; i < 4; ++i) {
      af[i]  = *(const bf16x8*)&a_sm[(wr * 64 + i * 16 + r) * 32 + ((q ^ cx) * 8)];
      bfv[i] = *(const bf16x8*)&b_sm[(wc * 64 + i * 16 + r) * 32 + ((q ^ cx) * 8)];
    }
#pragma unroll
    for (int i = 0; i < 4; ++i)
#pragma unroll
      for (int j = 0; j < 4; ++j)
        acc[i][j] = __builtin_amdgcn_mfma_f32_16x16x32_bf16(af[i], bfv[j], acc[i][j], 0, 0, 0);
  }

#pragma unroll
  for (int i = 0; i < 4; ++i) {
#pragma unroll
    for (int j = 0; j < 4; ++j) {
      const int n = n0 + wc * 64 + j * 16 + r;
      const float bv = bias ? bias[n] : 0.f;
#pragma unroll
      for (int v = 0; v < 4; ++v) {
        const int m = m0 + wr * 64 + i * 16 + q * 4 + v;
        if (m < Mvalid) {
          const float val = acc[i][j][v] + bv;
          if (Cf) Cf[(size_t)m * ldc + n] = val;
          else    Cb[(size_t)m * ldc + n] = f2bf(val);
        }
      }
    }
  }
}

// ======================================================================
// Big logits GEMM: C[4032,32000] = Afin[4032,768] * Wout[32000,768]^T + bout.
// 256x256 tile, BK=32, 512 threads (8 waves 2Mx4N, 128x64 per wave).
// Triple-buffered LDS ring (96KB), prefetch distance 2, counted vmcnt
// (never 0 in steady state), raw s_barrier, setprio around MFMA cluster,
// XCD-chunked block swizzle, nontemporal C stores.
// Granule XOR swizzle identical in structure to gemm_nt's (proven 0-conflict).
// ======================================================================
__global__ __launch_bounds__(512, 2) void gemm_big(
    const u16* __restrict__ A,   // [4096][768] bf16
    const u16* __restrict__ W,   // [32000][768] bf16
    const float* __restrict__ bias,
    float* __restrict__ C)       // ldc = V, rows < 4032 valid
{
  extern __shared__ u16 sm[];    // 3 * 16384 u16 = 96 KiB
  const int tid = threadIdx.x;
  const int lane = tid & 63, w = tid >> 6;
  const int wr = w >> 2, wc = w & 3;
  const int r = lane & 15, q = lane >> 4;

  // XCD-chunked bijective swizzle: 2000 blocks, 8 XCDs, 250 per XCD.
  const int bid = blockIdx.x;
  const int swz = (bid & 7) * 250 + (bid >> 3);
  const int mt = swz & 15, nt = swz >> 4;        // 16 x 125
  const int m0 = mt * 256, n0 = nt * 256;

  // staging: granule G = s*512 + tid; row = G>>2; phys gran = G&3 holds
  // logical gran (G&3) ^ ((row>>1)&3)  (same XOR family as gemm_nt).
  const int rowq = tid >> 2;                      // 0..127
  const int gl = (tid & 3) ^ ((tid >> 3) & 3);
  const u16* gA0 = A + (size_t)(m0 + rowq) * KO + gl * 8;
  const u16* gA1 = A + (size_t)(m0 + 128 + rowq) * KO + gl * 8;
  const u16* gW0 = W + (size_t)(n0 + rowq) * KO + gl * 8;
  const u16* gW1 = W + (size_t)(n0 + 128 + rowq) * KO + gl * 8;

  auto stage = [&](int c, int kt) {
    u16* ab = sm + c * 16384;
    u16* bb = ab + 8192;
    const int k0 = kt * 32;
    __builtin_amdgcn_global_load_lds((const AS1 void*)(gA0 + k0),
                                     (AS3 void*)(ab + w * 512), 16, 0, 0);
    __builtin_amdgcn_global_load_lds((const AS1 void*)(gW0 + k0),
                                     (AS3 void*)(bb + w * 512), 16, 0, 0);
    __builtin_amdgcn_global_load_lds((const AS1 void*)(gA1 + k0),
                                     (AS3 void*)(ab + 4096 + w * 512), 16, 0, 0);
    __builtin_amdgcn_global_load_lds((const AS1 void*)(gW1 + k0),
                                     (AS3 void*)(bb + 4096 + w * 512), 16, 0, 0);
  };

  // frag read offsets: row*32 + (q ^ ((r>>1)&3))*8 (u16 units)
  const int qa = q ^ ((r >> 1) & 3);
  int aoff[8], boff[4];
#pragma unroll
  for (int i = 0; i < 8; ++i) aoff[i] = (wr * 128 + i * 16 + r) * 32 + qa * 8;
#pragma unroll
  for (int j = 0; j < 4; ++j) boff[j] = (wc * 64 + j * 16 + r) * 32 + qa * 8;

  f32x4 acc[8][4] = {};

  stage(0, 0);
  stage(1, 1);
  stage(2, 2);

  for (int kt = 0; kt < 24; ++kt) {
    const int c = kt % 3;
    // counted wait: tiles kt+1, kt+2 stay in flight (4 loads each)
    if (kt < 22)      asm volatile("s_waitcnt vmcnt(8)" ::: "memory");
    else if (kt < 23) asm volatile("s_waitcnt vmcnt(4)" ::: "memory");
    else              asm volatile("s_waitcnt vmcnt(0)" ::: "memory");
    __builtin_amdgcn_s_barrier();
    __builtin_amdgcn_sched_barrier(0);

    const u16* ab = sm + c * 16384;
    const u16* bb = ab + 8192;
    bf16x8 fa[8], fb[4];
#pragma unroll
    for (int i = 0; i < 8; ++i) fa[i] = *(const bf16x8*)&ab[aoff[i]];
#pragma unroll
    for (int j = 0; j < 4; ++j) fb[j] = *(const bf16x8*)&bb[boff[j]];
    asm volatile("s_waitcnt lgkmcnt(0)" ::: "memory");
    __builtin_amdgcn_sched_barrier(0);
    __builtin_amdgcn_s_barrier();       // all waves done reading buf c
    __builtin_amdgcn_sched_barrier(0);

    if (kt + 3 < 24) stage(c, kt + 3);  // refill freed buffer

    __builtin_amdgcn_s_setprio(1);
#pragma unroll
    for (int i = 0; i < 8; ++i)
#pragma unroll
      for (int j = 0; j < 4; ++j)
        acc[i][j] = __builtin_amdgcn_mfma_f32_16x16x32_bf16(fa[i], fb[j], acc[i][j], 0, 0, 0);
    __builtin_amdgcn_s_setprio(0);
  }

  // epilogue: bias + nontemporal fp32 stores (stream, don't pollute L2)
#pragma unroll
  for (int j = 0; j < 4; ++j) {
    const int n = n0 + wc * 64 + j * 16 + r;
    const float bv = bias[n];
#pragma unroll
    for (int i = 0; i < 8; ++i) {
      const int mbase = m0 + wr * 128 + i * 16 + q * 4;
#pragma unroll
      for (int v = 0; v < 4; ++v) {
        const int m = mbase + v;
        if (m < MD)
          __builtin_nontemporal_store(acc[i][j][v] + bv, &C[(size_t)m * V + n]);
      }
    }
  }
}

// ======================================================================
// Persistent GRU. 32 WGs, WG w owns H-slice [w*16, w*16+16).
// Cross-WG coherence via relaxed SYSTEM-scope 8B atomics; no fences.
// ======================================================================
__global__ __launch_bounds__(256) void gru_kernel(
    const u16* __restrict__ xgates,     // [steps*64, 1536] bf16 (incl. b_ih)
    const float* __restrict__ Whh,      // [1536, 512] fp32
    const float* __restrict__ bhh,      // [1536]
    const int* __restrict__ lens,       // null => no masking
    const float* __restrict__ h0,       // null => zeros
    float* __restrict__ hf0, float* __restrict__ hf1,
    u16* __restrict__ hb0, u16* __restrict__ hb1,
    int steps, unsigned* __restrict__ bar,
    u16* __restrict__ outA)             // null, or Afinal: [m*768 + j] bf16
{
  extern __shared__ char smem[];
  u16* whh_sm = (u16*)smem;                        // [48][520] bf16
  u16* h_sm   = (u16*)(smem + 48 * 520 * 2);       // [64][520] bf16
  float* hg_sm = (float*)(smem + 112 * 520 * 2);   // [64][3][16] fp32

  const int tid = threadIdx.x;
  const int lane = tid & 63;
  const int w = tid >> 6;
  const int jbase = blockIdx.x * 16;
  const int r = lane & 15, q = lane >> 4;

  // preload this WG's 48 Whh rows (r,z,n gates for its 16 H-indices)
  for (int e = tid; e < 48 * 512; e += 256) {
    int rowl = e >> 9, k = e & 511;
    int g = rowl >> 4, jl = rowl & 15;
    whh_sm[rowl * 520 + k] = f2bf(Whh[(size_t)(g * 512 + jbase + jl) * 512 + k]);
  }

  // elementwise ownership: thread -> (b = tid>>2, 4 consecutive jl)
  const int eb  = tid >> 2;
  const int jl0 = (tid & 3) * 4;
  const int jg0 = jbase + jl0;

  // init h slice (bf16 part via coherent stores)
  {
    u16 hb4[4];
#pragma unroll
    for (int v2 = 0; v2 < 4; ++v2) {
      float v = h0 ? h0[eb * 512 + jg0 + v2] : 0.f;
      hf0[eb * 512 + jg0 + v2] = v;
      hb4[v2] = f2bf(v);
    }
    u64 pack = (u64)hb4[0] | ((u64)hb4[1] << 16) | ((u64)hb4[2] << 32) |
               ((u64)hb4[3] << 48);
    st_coh_u64((u64*)&hb0[eb * 512 + jg0], pack);
  }
  asm volatile("s_waitcnt vmcnt(0)" ::: "memory");
  __syncthreads();
  if (tid == 0) {
    __hip_atomic_fetch_add(bar, 1u, __ATOMIC_RELAXED, __HIP_MEMORY_SCOPE_SYSTEM);
    while (__hip_atomic_load(bar, __ATOMIC_RELAXED, __HIP_MEMORY_SCOPE_SYSTEM) < 32u)
      __builtin_amdgcn_s_sleep(1);
  }
  __syncthreads();

  for (int t = 0; t < steps; ++t) {
    const float* hf_cur = (t & 1) ? hf1 : hf0;
    const u16*   hb_cur = (t & 1) ? hb1 : hb0;
    float*       hf_nxt = (t & 1) ? hf0 : hf1;
    u16*         hb_nxt = (t & 1) ? hb0 : hb1;

    // prefetch this step's input gates early (plain cached loads; no h dep)
    const size_t mrow = (size_t)t * 64 + eb;
    u64 xrv = *(const u64*)&xgates[mrow * 1536 + jg0];
    u64 xzv = *(const u64*)&xgates[mrow * 1536 + 512 + jg0];
    u64 xnv = *(const u64*)&xgates[mrow * 1536 + 1024 + jg0];

    // stage full h (bf16) into LDS: 32 coherent 8B loads in flight/thread
    {
      const u64* src = (const u64*)hb_cur;   // 8192 chunks = 64 rows x 128
      u64 v[32];
#pragma unroll
      for (int i = 0; i < 32; ++i) v[i] = ld_coh_u64(src + i * 256 + tid);
#pragma unroll
      for (int i = 0; i < 32; ++i) {
        int c = i * 256 + tid;
        int row = c >> 7, c4 = c & 127;
        *(u64*)&h_sm[row * 520 + c4 * 4] = v[i];
      }
    }
    __syncthreads();

    // hg[b, 48 rows] = h @ Whh_slice^T ; wave w -> b-block w*16
    f32x4 acc[3] = {};
#pragma unroll
    for (int kt = 0; kt < 16; ++kt) {
      bf16x8 a = *(const bf16x8*)&h_sm[(w * 16 + r) * 520 + kt * 32 + q * 8];
#pragma unroll
      for (int g = 0; g < 3; ++g) {
        bf16x8 bb = *(const bf16x8*)&whh_sm[(g * 16 + r) * 520 + kt * 32 + q * 8];
        acc[g] = __builtin_amdgcn_mfma_f32_16x16x32_bf16(a, bb, acc[g], 0, 0, 0);
      }
    }
#pragma unroll
    for (int g = 0; g < 3; ++g)
#pragma unroll
      for (int v = 0; v < 4; ++v)
        hg_sm[((w * 16 + q * 4 + v) * 3 + g) * 16 + r] = acc[g][v];
    __syncthreads();

    // elementwise gates (fp32 carry path), 4 consecutive j per thread
    {
      u16 hb4[4];
#pragma unroll
      for (int v2 = 0; v2 < 4; ++v2) {
        const int jl = jl0 + v2, jg = jg0 + v2;
        float xr = bf2f((u16)(xrv >> (16 * v2)));
        float xz = bf2f((u16)(xzv >> (16 * v2)));
        float xn = bf2f((u16)(xnv >> (16 * v2)));
        float hr = hg_sm[(eb * 3 + 0) * 16 + jl] + bhh[jg];
        float hz = hg_sm[(eb * 3 + 1) * 16 + jl] + bhh[512 + jg];
        float hn = hg_sm[(eb * 3 + 2) * 16 + jl] + bhh[1024 + jg];
        float rg = 1.f / (1.f + __expf(-(xr + hr)));
        float zg = 1.f / (1.f + __expf(-(xz + hz)));
        float ng = tanhf(xn + rg * hn);
        float hold = hf_cur[eb * 512 + jg];
        float hnew = (1.f - zg) * ng + zg * hold;
        if (lens && t >= lens[eb]) hnew = hold;
        hf_nxt[eb * 512 + jg] = hnew;
        hb4[v2] = f2bf(hnew);
        if (outA) outA[mrow * (size_t)KO + jg] = hb4[v2];
      }
      u64 pack = (u64)hb4[0] | ((u64)hb4[1] << 16) | ((u64)hb4[2] << 32) |
                 ((u64)hb4[3] << 48);
      st_coh_u64((u64*)&hb_nxt[eb * 512 + jg0], pack);
    }

    // release: drain coherent stores, then count in; spin until all 32 in
    asm volatile("s_waitcnt vmcnt(0)" ::: "memory");
    __syncthreads();
    if (tid == 0) {
      __hip_atomic_fetch_add(bar, 1u, __ATOMIC_RELAXED, __HIP_MEMORY_SCOPE_SYSTEM);
      const unsigned tgt = 32u * (unsigned)(t + 2);
      while (__hip_atomic_load(bar, __ATOMIC_RELAXED, __HIP_MEMORY_SCOPE_SYSTEM) < tgt)
        __builtin_amdgcn_s_sleep(1);
    }
    __syncthreads();
  }
}

// ======================================================================
// Loss: one WG per row; online logsumexp; masked NLL accumulate.
// ======================================================================
__global__ __launch_bounds__(256) void loss_rows(
    const float* __restrict__ logits, const int* __restrict__ y,
    float* __restrict__ accum)
{
  __shared__ float sm_m[256], sm_s[256];
  const int row = blockIdx.x;
  const float* rp = logits + (size_t)row * V;
  const int tid = threadIdx.x;
  float m = -1e30f, s = 0.f;
  for (int it = 0; it < 32; ++it) {
    int i4 = tid + it * 256;
    if (i4 < V / 4) {
      float4 x = ((const float4*)rp)[i4];
      float mx = fmaxf(fmaxf(x.x, x.y), fmaxf(x.z, x.w));
      float mn = fmaxf(m, mx);
      s = s * __expf(m - mn) + __expf(x.x - mn) + __expf(x.y - mn) +
          __expf(x.z - mn) + __expf(x.w - mn);
      m = mn;
    }
  }
  sm_m[tid] = m; sm_s[tid] = s;
  __syncthreads();
  for (int off = 128; off > 0; off >>= 1) {
    if (tid < off) {
      float m2 = sm_m[tid + off], s2 = sm_s[tid + off];
      float mn = fmaxf(sm_m[tid], m2);
      sm_s[tid] = sm_s[tid] * __expf(sm_m[tid] - mn) + s2 * __expf(m2 - mn);
      sm_m[tid] = mn;
    }
    __syncthreads();
  }
  if (tid == 0) {
    int tgt = y[row + 64];                 // y[1:] flattened
    float lse = sm_m[0] + __logf(sm_s[0]);
    float nll = lse - rp[tgt];
    if (tgt != 0) {                        // PAD = 0
      atomicAdd(&accum[0], nll);
      atomicAdd(&accum[1], 1.f);
    }
  }
}

__global__ void finalize_loss(const float* __restrict__ accum, float* __restrict__ out) {
  out[0] = accum[0] / fmaxf(accum[1], 1.f);
}

// ======================================================================
extern "C" void kernel_launch(void* const* d_in, const int* in_sizes, int n_in,
                              void* d_out, int out_size, void* d_ws, size_t ws_size,
                              hipStream_t stream)
{
  const int*   x      = (const int*)d_in[0];
  const int*   x_lens = (const int*)d_in[1];
  const int*   y      = (const int*)d_in[2];
  const float* emb    = (const float*)d_in[3];
  const float* eWih   = (const float*)d_in[4];
  const float* eWhh   = (const float*)d_in[5];
  const float* ebih   = (const float*)d_in[6];
  const float* ebhh   = (const float*)d_in[7];
  const float* dWih   = (const float*)d_in[8];
  const float* dWhh   = (const float*)d_in[9];
  const float* dbih   = (const float*)d_in[10];
  const float* dbhh   = (const float*)d_in[11];
  const float* Wout   = (const float*)d_in[12];
  const float* bout   = (const float*)d_in[13];
  float* out = (float*)d_out;

  char* ws = (char*)d_ws;
  unsigned* cnt  = (unsigned*)(ws + 0);            // [0]=bar_enc [1]=bar_dec
  float*    accum = (float*)(ws + 8);              // [0]=nll sum [1]=count
  u16*   Aenc = (u16*)(ws + 256);                  // 4096x256 bf16
  u16*   Afin = (u16*)(ws + 2097408);              // 4096x768 bf16
  u16*   xg   = (u16*)(ws + 8388864);              // 4096x1536 bf16
  u16*   yg   = (u16*)(ws + 20971776);             // 4096x1536 bf16
  u16*   WEb  = (u16*)(ws + 33554688);             // 1536x256
  u16*   WDb  = (u16*)(ws + 34341120);             // 1536x256
  u16*   WOb  = (u16*)(ws + 35127552);             // 32000x768
  float* hEf  = (float*)(ws + 84279552);           // 2 x [64x512] fp32
  u16*   hEb  = (u16*)(ws + 84541696);             // 2 x [64x512] bf16
  float* hDf  = (float*)(ws + 84672768);
  u16*   hDb  = (u16*)(ws + 84934912);

  // dec_out[0] = zeros; barrier/accum init
  hipMemsetAsync(d_out, 0, (size_t)B * V * sizeof(float), stream);
  hipMemsetAsync(ws, 0, 256, stream);

  cast_weights<<<99072, 256, 0, stream>>>(eWih, dWih, Wout, WEb, WDb, WOb);
  gather_emb<<<2 * MP, 256, 0, stream>>>(x, y, emb, Aenc, Afin);

  // input gates
  gemm_nt<<<dim3(32, 12), 256, 0, stream>>>(Aenc, E, WEb, E, ebih, E / 32,
                                            nullptr, xg, H3, MP);
  gemm_nt<<<dim3(32, 12), 256, 0, stream>>>(Afin + H, KO, WDb, E, dbih, E / 32,
                                            nullptr, yg, H3, MP);

  const size_t gru_lds = (size_t)112 * 520 * 2 + (size_t)64 * 3 * 16 * 4; // 128,768 B
  // encoder: 64 steps, masked by x_lens, h0 = 0; final h lands in buffer 0
  gru_kernel<<<32, 256, gru_lds, stream>>>(xg, eWhh, ebhh, x_lens, nullptr,
      hEf, hEf + 32768, hEb, hEb + 32768, T, cnt + 0, nullptr);
  // decoder: 63 steps, h0 = encoder final (hEf buf0), dumps dec_h into Afinal
  gru_kernel<<<32, 256, gru_lds, stream>>>(yg, dWhh, dbhh, nullptr, hEf,
      hDf, hDf + 32768, hDb, hDb + 32768, T - 1, cnt + 1, Afin);

  // logits = [dec_h, ey] @ Wout^T + bout  -> d_out rows 1..63
  gemm_big<<<2000, 512, 3 * 16384 * sizeof(u16), stream>>>(
      Afin, WOb, bout, out + OUT_LOGITS_OFF);

  loss_rows<<<MD, 256, 0, stream>>>(out + OUT_LOGITS_OFF, y, accum);
  finalize_loss<<<1, 1, 0, stream>>>(accum, out + OUT_LOSS_OFF);
}

// Round 3
// 1784.983 us; speedup vs baseline: 1.5006x; 1.0324x over previous
//
#include <hip/hip_runtime.h>

typedef unsigned short u16;
typedef unsigned long long u64;
typedef __bf16 bf16x8 __attribute__((ext_vector_type(8)));
typedef float f32x4 __attribute__((ext_vector_type(4)));

#define AS1 __attribute__((address_space(1)))
#define AS3 __attribute__((address_space(3)))

__device__ __forceinline__ u16 f2bf(float f) {
  unsigned u = __builtin_bit_cast(unsigned, f);
  unsigned r = (u + 0x7FFFu + ((u >> 16) & 1u)) >> 16;
  return (u16)r;
}
__device__ __forceinline__ float bf2f(u16 h) {
  unsigned u = ((unsigned)h) << 16;
  return __builtin_bit_cast(float, u);
}

// Coherent (MALL-level, sc0 sc1) 8B data movement for cross-WG hand-off.
__device__ __forceinline__ u64 ld_coh_u64(const u64* p) {
  return __hip_atomic_load(p, __ATOMIC_RELAXED, __HIP_MEMORY_SCOPE_SYSTEM);
}
__device__ __forceinline__ void st_coh_u64(u64* p, u64 v) {
  __hip_atomic_store(p, v, __ATOMIC_RELAXED, __HIP_MEMORY_SCOPE_SYSTEM);
}

// ---- problem constants ----
constexpr int V = 32000, E = 256, H = 512, T = 64, B = 64;
constexpr int H3 = 3 * H;            // 1536
constexpr int MP = T * B;            // 4096 (padded M)
constexpr int MD = (T - 1) * B;      // 4032 (valid decoder rows)
constexpr int KO = H + E;            // 768
constexpr long long OUT_LOGITS_OFF = (long long)B * V;    // 2,048,000
constexpr long long OUT_LOSS_OFF  = (long long)T * B * V; // 131,072,000

// ======================================================================
// Weight cast fp32 -> bf16 (enc_Wih, dec_Wih, Wout)
// ======================================================================
__global__ __launch_bounds__(256) void cast_weights(
    const float* __restrict__ eW, const float* __restrict__ dW,
    const float* __restrict__ oW,
    u16* __restrict__ eWb, u16* __restrict__ dWb, u16* __restrict__ oWb)
{
  size_t i = (size_t)blockIdx.x * 256 + threadIdx.x;
  const size_t S1 = (size_t)H3 * E;       // 393216
  if (i < S1) { eWb[i] = f2bf(eW[i]); return; }
  i -= S1;
  if (i < S1) { dWb[i] = f2bf(dW[i]); return; }
  i -= S1;
  if (i < (size_t)V * KO) oWb[i] = f2bf(oW[i]);
}

// ======================================================================
// Embedding gather: Aenc[4096][256] (bf16), Afinal[.][512..768) = emb[y[:-1]]
// ======================================================================
__global__ __launch_bounds__(256) void gather_emb(
    const int* __restrict__ x, const int* __restrict__ y,
    const float* __restrict__ emb,
    u16* __restrict__ Aenc, u16* __restrict__ Afin)
{
  const int blk = blockIdx.x, e = threadIdx.x;
  if (blk < MP) {
    int tok = x[blk];
    Aenc[(size_t)blk * E + e] = f2bf(emb[(size_t)tok * E + e]);
  } else {
    int m = blk - MP;
    int tok = (m < MD) ? y[m] : 0;
    Afin[(size_t)m * KO + H + e] = f2bf(emb[(size_t)tok * E + e]);
  }
}

// ======================================================================
// NT GEMM (small): 128x128 tile, BK=32, m97 structure. Gate GEMMs only.
// ======================================================================
__global__ __launch_bounds__(256) void gemm_nt(
    const u16* __restrict__ A, int lda,
    const u16* __restrict__ W, int ldw,
    const float* __restrict__ bias,
    int Kt,                                   // K / 32
    float* __restrict__ Cf, u16* __restrict__ Cb,  // exactly one non-null
    int ldc, int Mvalid)
{
  __shared__ u16 a_sm[128 * 32];
  __shared__ u16 b_sm[128 * 32];
  const int tid = threadIdx.x;
  const int lane = tid & 63;
  const int w = tid >> 6;
  const int m0 = blockIdx.x * 128;
  const int n0 = blockIdx.y * 128;
  const int srow = lane >> 2;                        // staging row within 16
  const int gc = (lane & 3) ^ ((lane >> 3) & 3);     // swizzled global chunk
  const int r = lane & 15;
  const int q = lane >> 4;
  const int cx = (r >> 1) & 3;                       // frag chunk xor
  const int wr = w >> 1, wc = w & 1;

  f32x4 acc[4][4] = {};

  for (int kt = 0; kt < Kt; ++kt) {
    const int k0 = kt * 32;
    __syncthreads();
#pragma unroll
    for (int rr = 0; rr < 2; ++rr) {
      const int rbase = w * 32 + rr * 16;
      const u16* gA = A + (size_t)(m0 + rbase + srow) * lda + k0 + gc * 8;
      const u16* gB = W + (size_t)(n0 + rbase + srow) * ldw + k0 + gc * 8;
      __builtin_amdgcn_global_load_lds((const AS1 void*)gA,
                                       (AS3 void*)&a_sm[rbase * 32], 16, 0, 0);
      __builtin_amdgcn_global_load_lds((const AS1 void*)gB,
                                       (AS3 void*)&b_sm[rbase * 32], 16, 0, 0);
    }
    __syncthreads();
    bf16x8 af[4], bfv[4];
#pragma unroll
    for (int i = 0; i < 4; ++i) {
      af[i]  = *(const bf16x8*)&a_sm[(wr * 64 + i * 16 + r) * 32 + ((q ^ cx) * 8)];
      bfv[i] = *(const bf16x8*)&b_sm[(wc * 64 + i * 16 + r) * 32 + ((q ^ cx) * 8)];
    }
#pragma unroll
    for (int i = 0; i < 4; ++i)
#pragma unroll
      for (int j = 0; j < 4; ++j)
        acc[i][j] = __builtin_amdgcn_mfma_f32_16x16x32_bf16(af[i], bfv[j], acc[i][j], 0, 0, 0);
  }

#pragma unroll
  for (int i = 0; i < 4; ++i) {
#pragma unroll
    for (int j = 0; j < 4; ++j) {
      const int n = n0 + wc * 64 + j * 16 + r;
      const float bv = bias ? bias[n] : 0.f;
#pragma unroll
      for (int v = 0; v < 4; ++v) {
        const int m = m0 + wr * 64 + i * 16 + q * 4 + v;
        if (m < Mvalid) {
          const float val = acc[i][j][v] + bv;
          if (Cf) Cf[(size_t)m * ldc + n] = val;
          else    Cb[(size_t)m * ldc + n] = f2bf(val);
        }
      }
    }
  }
}

// ======================================================================
// GRU step body, templated on block size NT (256 standalone / 512 fused).
// 32 WGs, WG `blk` owns H-slice [blk*16, blk*16+16).
// Cross-WG coherence via relaxed SYSTEM-scope 8B atomics; no fences.
// bar counts 32 per phase: after init bar=32, after step t bar=32*(t+2).
// ======================================================================
template<int NT>
__device__ __forceinline__ void gru_body(
    const u16* __restrict__ xgates,     // [steps*64, 1536] bf16 (incl. b_ih)
    const float* __restrict__ Whh,      // [1536, 512] fp32
    const float* __restrict__ bhh,      // [1536]
    const int* __restrict__ lens,       // null => no masking
    const float* __restrict__ h0,       // null => zeros
    float* __restrict__ hf0, float* __restrict__ hf1,
    u16* __restrict__ hb0, u16* __restrict__ hb1,
    int steps, unsigned* __restrict__ bar,
    u16* __restrict__ outA,             // null, or Afinal: [m*768 + j] bf16
    int blk, char* smem)
{
  u16* whh_sm = (u16*)smem;                        // [48][520] bf16
  u16* h_sm   = (u16*)(smem + 48 * 520 * 2);       // [64][520] bf16
  float* hg_sm = (float*)(smem + 112 * 520 * 2);   // [64][3][16] fp32

  const int tid = threadIdx.x;
  const int lane = tid & 63;
  const int w = tid >> 6;
  const int jbase = blk * 16;
  const int r = lane & 15, q = lane >> 4;

  // preload this WG's 48 Whh rows (r,z,n gates for its 16 H-indices)
  for (int e = tid; e < 48 * 512; e += NT) {
    int rowl = e >> 9, k = e & 511;
    int g = rowl >> 4, jl = rowl & 15;
    whh_sm[rowl * 520 + k] = f2bf(Whh[(size_t)(g * 512 + jbase + jl) * 512 + k]);
  }

  // elementwise ownership (threads 0..255): thread -> (b, 4 consecutive jl)
  const int eb  = (tid & 255) >> 2;
  const int jl0 = (tid & 3) * 4;
  const int jg0 = jbase + jl0;

  // init h slice (bf16 part via coherent stores)
  if (tid < 256) {
    u16 hb4[4];
#pragma unroll
    for (int v2 = 0; v2 < 4; ++v2) {
      float v = h0 ? h0[eb * 512 + jg0 + v2] : 0.f;
      hf0[eb * 512 + jg0 + v2] = v;
      hb4[v2] = f2bf(v);
    }
    u64 pack = (u64)hb4[0] | ((u64)hb4[1] << 16) | ((u64)hb4[2] << 32) |
               ((u64)hb4[3] << 48);
    st_coh_u64((u64*)&hb0[eb * 512 + jg0], pack);
  }
  asm volatile("s_waitcnt vmcnt(0)" ::: "memory");
  __syncthreads();
  if (tid == 0) {
    __hip_atomic_fetch_add(bar, 1u, __ATOMIC_RELAXED, __HIP_MEMORY_SCOPE_SYSTEM);
    while (__hip_atomic_load(bar, __ATOMIC_RELAXED, __HIP_MEMORY_SCOPE_SYSTEM) < 32u)
      __builtin_amdgcn_s_sleep(1);
  }
  __syncthreads();

  for (int t = 0; t < steps; ++t) {
    const float* hf_cur = (t & 1) ? hf1 : hf0;
    const u16*   hb_cur = (t & 1) ? hb1 : hb0;
    float*       hf_nxt = (t & 1) ? hf0 : hf1;
    u16*         hb_nxt = (t & 1) ? hb0 : hb1;

    // prefetch this step's input gates early (plain cached loads; no h dep)
    u64 xrv = 0, xzv = 0, xnv = 0;
    const size_t mrow = (size_t)t * 64 + eb;
    if (tid < 256) {
      xrv = *(const u64*)&xgates[mrow * 1536 + jg0];
      xzv = *(const u64*)&xgates[mrow * 1536 + 512 + jg0];
      xnv = *(const u64*)&xgates[mrow * 1536 + 1024 + jg0];
    }

    // stage full h (bf16) into LDS: coherent 8B loads, all NT threads
    {
      constexpr int NCH = 8192 / NT;     // 8192 u64 chunks = 64 rows x 128
      const u64* src = (const u64*)hb_cur;
      u64 v[NCH];
#pragma unroll
      for (int i = 0; i < NCH; ++i) v[i] = ld_coh_u64(src + i * NT + tid);
#pragma unroll
      for (int i = 0; i < NCH; ++i) {
        int c = i * NT + tid;
        int row = c >> 7, c4 = c & 127;
        *(u64*)&h_sm[row * 520 + c4 * 4] = v[i];
      }
    }
    __syncthreads();

    // hg[b, 48 rows] = h @ Whh_slice^T ; wave w (0..3) -> b-block w*16
    if (w < 4) {
      f32x4 acc[3] = {};
#pragma unroll
      for (int kt = 0; kt < 16; ++kt) {
        bf16x8 a = *(const bf16x8*)&h_sm[(w * 16 + r) * 520 + kt * 32 + q * 8];
#pragma unroll
        for (int g = 0; g < 3; ++g) {
          bf16x8 bb = *(const bf16x8*)&whh_sm[(g * 16 + r) * 520 + kt * 32 + q * 8];
          acc[g] = __builtin_amdgcn_mfma_f32_16x16x32_bf16(a, bb, acc[g], 0, 0, 0);
        }
      }
#pragma unroll
      for (int g = 0; g < 3; ++g)
#pragma unroll
        for (int v = 0; v < 4; ++v)
          hg_sm[((w * 16 + q * 4 + v) * 3 + g) * 16 + r] = acc[g][v];
    }
    __syncthreads();

    // elementwise gates (fp32 carry path), 4 consecutive j per thread
    if (tid < 256) {
      u16 hb4[4];
#pragma unroll
      for (int v2 = 0; v2 < 4; ++v2) {
        const int jl = jl0 + v2, jg = jg0 + v2;
        float xr = bf2f((u16)(xrv >> (16 * v2)));
        float xz = bf2f((u16)(xzv >> (16 * v2)));
        float xn = bf2f((u16)(xnv >> (16 * v2)));
        float hr = hg_sm[(eb * 3 + 0) * 16 + jl] + bhh[jg];
        float hz = hg_sm[(eb * 3 + 1) * 16 + jl] + bhh[512 + jg];
        float hn = hg_sm[(eb * 3 + 2) * 16 + jl] + bhh[1024 + jg];
        float rg = 1.f / (1.f + __expf(-(xr + hr)));
        float zg = 1.f / (1.f + __expf(-(xz + hz)));
        float ng = tanhf(xn + rg * hn);
        float hold = hf_cur[eb * 512 + jg];
        float hnew = (1.f - zg) * ng + zg * hold;
        if (lens && t >= lens[eb]) hnew = hold;
        hf_nxt[eb * 512 + jg] = hnew;
        hb4[v2] = f2bf(hnew);
      }
      u64 pack = (u64)hb4[0] | ((u64)hb4[1] << 16) | ((u64)hb4[2] << 32) |
                 ((u64)hb4[3] << 48);
      if (outA) st_coh_u64((u64*)&outA[mrow * (size_t)KO + jg0], pack);
      st_coh_u64((u64*)&hb_nxt[eb * 512 + jg0], pack);
    }

    // release: drain coherent stores, then count in; spin until all 32 in
    asm volatile("s_waitcnt vmcnt(0)" ::: "memory");
    __syncthreads();
    if (tid == 0) {
      __hip_atomic_fetch_add(bar, 1u, __ATOMIC_RELAXED, __HIP_MEMORY_SCOPE_SYSTEM);
      const unsigned tgt = 32u * (unsigned)(t + 2);
      while (__hip_atomic_load(bar, __ATOMIC_RELAXED, __HIP_MEMORY_SCOPE_SYSTEM) < tgt)
        __builtin_amdgcn_s_sleep(1);
    }
    __syncthreads();
  }
}

__global__ __launch_bounds__(256) void gru_kernel(
    const u16* __restrict__ xgates, const float* __restrict__ Whh,
    const float* __restrict__ bhh, const int* __restrict__ lens,
    const float* __restrict__ h0,
    float* __restrict__ hf0, float* __restrict__ hf1,
    u16* __restrict__ hb0, u16* __restrict__ hb1,
    int steps, unsigned* __restrict__ bar, u16* __restrict__ outA)
{
  extern __shared__ char smem[];
  gru_body<256>(xgates, Whh, bhh, lens, h0, hf0, hf1, hb0, hb1, steps, bar,
                outA, blockIdx.x, smem);
}

// ======================================================================
// Fused decoder GRU + logits GEMM. Grid = 256 blocks x 512 threads,
// 1 block/CU (LDS 128.7KB) => all blocks co-resident by construction.
// Blocks 0..31: decoder GRU (outA -> Afin dec_h half, coherent stores).
// Blocks 32..255: persistent 256x256 GEMM workers, mt-major tile walk,
// each M-tile gated on decoder progress counter (coherent reads only
// touch rows already drained to MALL before the counter bump).
// ======================================================================
__global__ __launch_bounds__(512, 2) void fused_dec(
    const u16* __restrict__ yg, const float* __restrict__ Whh,
    const float* __restrict__ bhh, const float* __restrict__ h0,
    float* __restrict__ hf0, float* __restrict__ hf1,
    u16* __restrict__ hb0, u16* __restrict__ hb1,
    unsigned* __restrict__ bar,
    u16* __restrict__ afin,            // GRU outA AND gemm A (4096x768 bf16)
    const u16* __restrict__ W,         // [32000][768] bf16
    const float* __restrict__ bias,
    float* __restrict__ C)             // ldc = V, rows < 4032 valid
{
  extern __shared__ char smem[];

  if (blockIdx.x < 32) {
    gru_body<512>(yg, Whh, bhh, nullptr, h0, hf0, hf1, hb0, hb1, T - 1, bar,
                  afin, blockIdx.x, smem);
    return;
  }

  // ---- persistent GEMM worker ----
  u16* sm = (u16*)smem;                // 3 * 16384 u16 = 96 KiB used
  const int wid = blockIdx.x - 32;     // 0..223
  const int tid = threadIdx.x;
  const int lane = tid & 63, w = tid >> 6;
  const int wr = w >> 2, wc = w & 3;
  const int r = lane & 15, q = lane >> 4;
  const int rowq = tid >> 2;                      // 0..127
  const int gl = (tid & 3) ^ ((tid >> 3) & 3);    // swizzled global chunk
  const int qa = q ^ ((r >> 1) & 3);

  int aoff[8], boff[4];
#pragma unroll
  for (int i = 0; i < 8; ++i) aoff[i] = (wr * 128 + i * 16 + r) * 32 + qa * 8;
#pragma unroll
  for (int j = 0; j < 4; ++j) boff[j] = (wc * 64 + j * 16 + r) * 32 + qa * 8;

  for (int tile = wid; tile < 2000; tile += 224) {
    const int mt = tile / 125, nt = tile - mt * 125;
    const int m0 = mt * 256, n0 = nt * 256;

    // gate: decoder must have produced rows [m0, m0+256) of afin
    int need = 4 * mt + 3; if (need > 62) need = 62;
    const unsigned tgt = 32u * (unsigned)(need + 2);
    if (tid == 0) {
      while (__hip_atomic_load(bar, __ATOMIC_RELAXED, __HIP_MEMORY_SCOPE_SYSTEM) < tgt)
        __builtin_amdgcn_s_sleep(16);
    }
    __syncthreads();

    const u16* gA0 = afin + (size_t)(m0 + rowq) * KO + gl * 8;
    const u16* gA1 = afin + (size_t)(m0 + 128 + rowq) * KO + gl * 8;
    const u16* gW0 = W + (size_t)(n0 + rowq) * KO + gl * 8;
    const u16* gW1 = W + (size_t)(n0 + 128 + rowq) * KO + gl * 8;

    auto stage = [&](int c, int kt) {
      u16* ab = sm + c * 16384;
      u16* bb = ab + 8192;
      const int k0 = kt * 32;
      __builtin_amdgcn_global_load_lds((const AS1 void*)(gA0 + k0),
                                       (AS3 void*)(ab + w * 512), 16, 0, 0);
      __builtin_amdgcn_global_load_lds((const AS1 void*)(gW0 + k0),
                                       (AS3 void*)(bb + w * 512), 16, 0, 0);
      __builtin_amdgcn_global_load_lds((const AS1 void*)(gA1 + k0),
                                       (AS3 void*)(ab + 4096 + w * 512), 16, 0, 0);
      __builtin_amdgcn_global_load_lds((const AS1 void*)(gW1 + k0),
                                       (AS3 void*)(bb + 4096 + w * 512), 16, 0, 0);
    };

    f32x4 acc[8][4] = {};

    stage(0, 0);
    stage(1, 1);
    stage(2, 2);

    for (int kt = 0; kt < 24; ++kt) {
      const int c = kt % 3;
      if (kt < 22)      asm volatile("s_waitcnt vmcnt(8)" ::: "memory");
      else if (kt < 23) asm volatile("s_waitcnt vmcnt(4)" ::: "memory");
      else              asm volatile("s_waitcnt vmcnt(0)" ::: "memory");
      __builtin_amdgcn_s_barrier();
      __builtin_amdgcn_sched_barrier(0);

      const u16* ab = sm + c * 16384;
      const u16* bb = ab + 8192;
      bf16x8 fa[8], fb[4];
#pragma unroll
      for (int i = 0; i < 8; ++i) fa[i] = *(const bf16x8*)&ab[aoff[i]];
#pragma unroll
      for (int j = 0; j < 4; ++j) fb[j] = *(const bf16x8*)&bb[boff[j]];
      asm volatile("s_waitcnt lgkmcnt(0)" ::: "memory");
      __builtin_amdgcn_sched_barrier(0);
      __builtin_amdgcn_s_barrier();       // all waves done reading buf c
      __builtin_amdgcn_sched_barrier(0);

      if (kt + 3 < 24) stage(c, kt + 3);  // refill freed buffer

      __builtin_amdgcn_s_setprio(1);
#pragma unroll
      for (int i = 0; i < 8; ++i)
#pragma unroll
        for (int j = 0; j < 4; ++j)
          acc[i][j] = __builtin_amdgcn_mfma_f32_16x16x32_bf16(fa[i], fb[j], acc[i][j], 0, 0, 0);
      __builtin_amdgcn_s_setprio(0);
    }

    // epilogue: bias + nontemporal fp32 stores
#pragma unroll
    for (int j = 0; j < 4; ++j) {
      const int n = n0 + wc * 64 + j * 16 + r;
      const float bv = bias[n];
#pragma unroll
      for (int i = 0; i < 8; ++i) {
        const int mbase = m0 + wr * 128 + i * 16 + q * 4;
#pragma unroll
        for (int v = 0; v < 4; ++v) {
          const int m = mbase + v;
          if (m < MD)
            __builtin_nontemporal_store(acc[i][j][v] + bv, &C[(size_t)m * V + n]);
        }
      }
    }
  }
}

// ======================================================================
// Loss: one WG per row; online logsumexp; masked NLL accumulate.
// ======================================================================
__global__ __launch_bounds__(256) void loss_rows(
    const float* __restrict__ logits, const int* __restrict__ y,
    float* __restrict__ accum)
{
  __shared__ float sm_m[256], sm_s[256];
  const int row = blockIdx.x;
  const float* rp = logits + (size_t)row * V;
  const int tid = threadIdx.x;
  float m = -1e30f, s = 0.f;
  for (int it = 0; it < 32; ++it) {
    int i4 = tid + it * 256;
    if (i4 < V / 4) {
      float4 x = ((const float4*)rp)[i4];
      float mx = fmaxf(fmaxf(x.x, x.y), fmaxf(x.z, x.w));
      float mn = fmaxf(m, mx);
      s = s * __expf(m - mn) + __expf(x.x - mn) + __expf(x.y - mn) +
          __expf(x.z - mn) + __expf(x.w - mn);
      m = mn;
    }
  }
  sm_m[tid] = m; sm_s[tid] = s;
  __syncthreads();
  for (int off = 128; off > 0; off >>= 1) {
    if (tid < off) {
      float m2 = sm_m[tid + off], s2 = sm_s[tid + off];
      float mn = fmaxf(sm_m[tid], m2);
      sm_s[tid] = sm_s[tid] * __expf(sm_m[tid] - mn) + s2 * __expf(m2 - mn);
      sm_m[tid] = mn;
    }
    __syncthreads();
  }
  if (tid == 0) {
    int tgt = y[row + 64];                 // y[1:] flattened
    float lse = sm_m[0] + __logf(sm_s[0]);
    float nll = lse - rp[tgt];
    if (tgt != 0) {                        // PAD = 0
      atomicAdd(&accum[0], nll);
      atomicAdd(&accum[1], 1.f);
    }
  }
}

__global__ void finalize_loss(const float* __restrict__ accum, float* __restrict__ out) {
  out[0] = accum[0] / fmaxf(accum[1], 1.f);
}

// ======================================================================
extern "C" void kernel_launch(void* const* d_in, const int* in_sizes, int n_in,
                              void* d_out, int out_size, void* d_ws, size_t ws_size,
                              hipStream_t stream)
{
  const int*   x      = (const int*)d_in[0];
  const int*   x_lens = (const int*)d_in[1];
  const int*   y      = (const int*)d_in[2];
  const float* emb    = (const float*)d_in[3];
  const float* eWih   = (const float*)d_in[4];
  const float* eWhh   = (const float*)d_in[5];
  const float* ebih   = (const float*)d_in[6];
  const float* ebhh   = (const float*)d_in[7];
  const float* dWih   = (const float*)d_in[8];
  const float* dWhh   = (const float*)d_in[9];
  const float* dbih   = (const float*)d_in[10];
  const float* dbhh   = (const float*)d_in[11];
  const float* Wout   = (const float*)d_in[12];
  const float* bout   = (const float*)d_in[13];
  float* out = (float*)d_out;

  char* ws = (char*)d_ws;
  unsigned* cnt  = (unsigned*)(ws + 0);            // [0]=bar_enc [1]=bar_dec
  float*    accum = (float*)(ws + 8);              // [0]=nll sum [1]=count
  u16*   Aenc = (u16*)(ws + 256);                  // 4096x256 bf16
  u16*   Afin = (u16*)(ws + 2097408);              // 4096x768 bf16
  u16*   xg   = (u16*)(ws + 8388864);              // 4096x1536 bf16
  u16*   yg   = (u16*)(ws + 20971776);             // 4096x1536 bf16
  u16*   WEb  = (u16*)(ws + 33554688);             // 1536x256
  u16*   WDb  = (u16*)(ws + 34341120);             // 1536x256
  u16*   WOb  = (u16*)(ws + 35127552);             // 32000x768
  float* hEf  = (float*)(ws + 84279552);           // 2 x [64x512] fp32
  u16*   hEb  = (u16*)(ws + 84541696);             // 2 x [64x512] bf16
  float* hDf  = (float*)(ws + 84672768);
  u16*   hDb  = (u16*)(ws + 84934912);

  // dec_out[0] = zeros; barrier/accum init
  hipMemsetAsync(d_out, 0, (size_t)B * V * sizeof(float), stream);
  hipMemsetAsync(ws, 0, 256, stream);

  cast_weights<<<99072, 256, 0, stream>>>(eWih, dWih, Wout, WEb, WDb, WOb);
  gather_emb<<<2 * MP, 256, 0, stream>>>(x, y, emb, Aenc, Afin);

  // input gates
  gemm_nt<<<dim3(32, 12), 256, 0, stream>>>(Aenc, E, WEb, E, ebih, E / 32,
                                            nullptr, xg, H3, MP);
  gemm_nt<<<dim3(32, 12), 256, 0, stream>>>(Afin + H, KO, WDb, E, dbih, E / 32,
                                            nullptr, yg, H3, MP);

  const size_t gru_lds = (size_t)112 * 520 * 2 + (size_t)64 * 3 * 16 * 4; // 128,768 B
  // encoder: 64 steps, masked by x_lens, h0 = 0; final h lands in buffer 0
  gru_kernel<<<32, 256, gru_lds, stream>>>(xg, eWhh, ebhh, x_lens, nullptr,
      hEf, hEf + 32768, hEb, hEb + 32768, T, cnt + 0, nullptr);

  // fused: decoder GRU (blocks 0..31) + logits GEMM workers (blocks 32..255)
  fused_dec<<<256, 512, gru_lds, stream>>>(yg, dWhh, dbhh, hEf,
      hDf, hDf + 32768, hDb, hDb + 32768, cnt + 1, Afin,
      WOb, bout, out + OUT_LOGITS_OFF);

  loss_rows<<<MD, 256, 0, stream>>>(out + OUT_LOGITS_OFF, y, accum);
  finalize_loss<<<1, 1, 0, stream>>>(accum, out + OUT_LOSS_OFF);
}